// Round 1
// baseline (127.963 us; speedup 1.0000x reference)
//
#include <hip/hip_runtime.h>
#include <math.h>

#define NPOS 512
#define NNEG 512
#define DIM  512
#define NB   1024
#define EPSV 1e-5f
#define COS_EPS 1e-8f

// ws layout (floats):
// [0,512)      inv_norm_pos
// [512,1024)   inv_norm_neg
// [1024,1536)  t1  (pos . w1)
// [1536,2560)  t2  (allv . w2), allv = [pos; neg]
// [2560, 2560+512*1024) S: cos matrix, cols [0,512)=pos.neg^T, [512,1024)=pos.pos^T
#define WS_S_OFF 2560

__device__ __forceinline__ float softplus_f(float x) {
    // log1p(exp(x)) stable
    return fmaxf(x, 0.f) + __logf(1.f + __expf(-fabsf(x)));
}

// ---------------- Kernel 1: norms + t1 + t2 + zero out ----------------
__global__ __launch_bounds__(256) void prep_kernel(
    const float* __restrict__ pos, const float* __restrict__ neg,
    const float* __restrict__ w, float* __restrict__ ws, float* __restrict__ out)
{
    int gtid = blockIdx.x * 256 + threadIdx.x;
    if (gtid == 0) out[0] = 0.f;
    int row  = gtid >> 6;     // one wave per row, 1024 rows
    int lane = threadIdx.x & 63;
    if (row >= NB) return;
    bool is_pos = row < NPOS;
    const float* r = is_pos ? pos + row * DIM : neg + (row - NPOS) * DIM;

    const float4* r4  = (const float4*)r + lane * 2;
    const float4* w14 = (const float4*)(w) + lane * 2;
    const float4* w24 = (const float4*)(w + DIM) + lane * 2;
    float4 a0 = r4[0],  a1 = r4[1];
    float4 u0 = w14[0], u1 = w14[1];
    float4 v0 = w24[0], v1 = w24[1];

    float ss  = a0.x*a0.x + a0.y*a0.y + a0.z*a0.z + a0.w*a0.w
              + a1.x*a1.x + a1.y*a1.y + a1.z*a1.z + a1.w*a1.w;
    float dw1 = a0.x*u0.x + a0.y*u0.y + a0.z*u0.z + a0.w*u0.w
              + a1.x*u1.x + a1.y*u1.y + a1.z*u1.z + a1.w*u1.w;
    float dw2 = a0.x*v0.x + a0.y*v0.y + a0.z*v0.z + a0.w*v0.w
              + a1.x*v1.x + a1.y*v1.y + a1.z*v1.z + a1.w*v1.w;

    #pragma unroll
    for (int off = 32; off; off >>= 1) {
        ss  += __shfl_xor(ss, off);
        dw1 += __shfl_xor(dw1, off);
        dw2 += __shfl_xor(dw2, off);
    }
    if (lane == 0) {
        float inv = 1.f / fmaxf(sqrtf(ss), COS_EPS);
        ws[row] = inv;                 // inv_pos[row] or inv_neg[row-512] (contiguous)
        ws[1536 + row] = dw2;          // t2[row] (allv order == [pos;neg])
        if (is_pos) ws[1024 + row] = dw1;  // t1
    }
}

// ---------------- Kernel 2: normalized cos matrix S (512 x 1024) ----------------
// Tile: 32 i x 64 j, k-chunks of 32. B = [neg; pos].
__global__ __launch_bounds__(256) void cosmat_kernel(
    const float* __restrict__ pos, const float* __restrict__ neg,
    float* __restrict__ ws)
{
    __shared__ float As[32][36];
    __shared__ float Bs[64][36];
    float* S = ws + WS_S_OFF;

    int tid = threadIdx.x;
    int i0 = blockIdx.y * 32;
    int j0 = blockIdx.x * 64;
    const float* Asrc = pos + i0 * DIM;
    const float* Bsrc = (j0 < NNEG) ? (neg + j0 * DIM) : (pos + (j0 - NNEG) * DIM);

    int lr = tid >> 3;          // 0..31
    int lc = (tid & 7) * 4;     // 0..28
    int ti = tid >> 4;          // 0..15 -> i pair
    int tj = tid & 15;          // 0..15 -> j strided by 16

    float acc[2][4] = {};

    for (int k0 = 0; k0 < DIM; k0 += 32) {
        *(float4*)&As[lr][lc]      = *(const float4*)(Asrc + lr * DIM + k0 + lc);
        *(float4*)&Bs[lr][lc]      = *(const float4*)(Bsrc + lr * DIM + k0 + lc);
        *(float4*)&Bs[lr + 32][lc] = *(const float4*)(Bsrc + (lr + 32) * DIM + k0 + lc);
        __syncthreads();
        #pragma unroll
        for (int k = 0; k < 32; k += 4) {
            float4 x0 = *(const float4*)&As[ti * 2 + 0][k];
            float4 x1 = *(const float4*)&As[ti * 2 + 1][k];
            #pragma unroll
            for (int jj = 0; jj < 4; jj++) {
                float4 b = *(const float4*)&Bs[tj + jj * 16][k];
                acc[0][jj] = fmaf(x0.x, b.x, fmaf(x0.y, b.y, fmaf(x0.z, b.z, fmaf(x0.w, b.w, acc[0][jj]))));
                acc[1][jj] = fmaf(x1.x, b.x, fmaf(x1.y, b.y, fmaf(x1.z, b.z, fmaf(x1.w, b.w, acc[1][jj]))));
            }
        }
        __syncthreads();
    }

    float invi0 = ws[i0 + ti * 2];
    float invi1 = ws[i0 + ti * 2 + 1];
    // invB: global B row jg: jg<512 -> neg -> ws[512+jg]; jg>=512 -> pos -> ws[jg-512]
    const float* invB = (j0 < NNEG) ? (ws + NNEG + j0) : (ws + (j0 - NNEG));
    #pragma unroll
    for (int jj = 0; jj < 4; jj++) {
        int j = tj + jj * 16;
        float invj = invB[j];
        S[(size_t)(i0 + ti * 2 + 0) * NB + j0 + j] = acc[0][jj] * invi0 * invj;
        S[(size_t)(i0 + ti * 2 + 1) * NB + j0 + j] = acc[1][jj] * invi1 * invj;
    }
}

// ---------------- Kernel 3: cos-part loss, wave per row ----------------
__global__ __launch_bounds__(256) void closs_kernel(
    const float* __restrict__ ws, float* __restrict__ out)
{
    const float* S = ws + WS_S_OFF;
    int wid  = (blockIdx.x * 256 + threadIdx.x) >> 6;
    int lane = threadIdx.x & 63;
    if (wid >= NPOS) return;
    const float* row = S + (size_t)wid * NB;

    // phase 1: deno = sum_j exp(cos_pn)
    const float4* p = (const float4*)row + lane * 2;
    float4 c0 = p[0], c1 = p[1];
    float deno = __expf(c0.x) + __expf(c0.y) + __expf(c0.z) + __expf(c0.w)
               + __expf(c1.x) + __expf(c1.y) + __expf(c1.z) + __expf(c1.w);
    #pragma unroll
    for (int off = 32; off; off >>= 1) deno += __shfl_xor(deno, off);

    // phase 2: sum_j log(deno + exp(c) + eps) - c  over pp columns
    const float4* q = (const float4*)(row + NNEG) + lane * 2;
    float4 d0 = q[0], d1 = q[1];
    float s = 0.f;
    s += __logf(deno + __expf(d0.x) + EPSV) - d0.x;
    s += __logf(deno + __expf(d0.y) + EPSV) - d0.y;
    s += __logf(deno + __expf(d0.z) + EPSV) - d0.z;
    s += __logf(deno + __expf(d0.w) + EPSV) - d0.w;
    s += __logf(deno + __expf(d1.x) + EPSV) - d1.x;
    s += __logf(deno + __expf(d1.y) + EPSV) - d1.y;
    s += __logf(deno + __expf(d1.z) + EPSV) - d1.z;
    s += __logf(deno + __expf(d1.w) + EPSV) - d1.w;
    #pragma unroll
    for (int off = 32; off; off >>= 1) s += __shfl_xor(s, off);
    if (lane == 0) atomicAdd(out, s);
}

// ---------------- Kernel 4: abs-diff t3 + BCE, tiled ----------------
// Tile 32 n x 64 m, k-chunks 32. B = allv = [pos; neg].
__global__ __launch_bounds__(256) void bce_kernel(
    const float* __restrict__ pos, const float* __restrict__ neg,
    const float* __restrict__ w, const float* __restrict__ lb,
    const float* __restrict__ ws, float* __restrict__ out)
{
    __shared__ float As[32][36];
    __shared__ float Bs[64][36];
    __shared__ float w3s[512];
    __shared__ float wsum[4];

    int tid = threadIdx.x;
    int i0 = blockIdx.y * 32;
    int j0 = blockIdx.x * 64;
    const float* Asrc = pos + i0 * DIM;
    const float* Bsrc = (j0 < NPOS) ? (pos + j0 * DIM) : (neg + (j0 - NPOS) * DIM);

    if (tid < 128) *(float4*)&w3s[tid * 4] = *(const float4*)(w + 2 * DIM + tid * 4);

    int lr = tid >> 3;
    int lc = (tid & 7) * 4;
    int ti = tid >> 4;
    int tj = tid & 15;

    float acc[2][4] = {};

    for (int k0 = 0; k0 < DIM; k0 += 32) {
        *(float4*)&As[lr][lc]      = *(const float4*)(Asrc + lr * DIM + k0 + lc);
        *(float4*)&Bs[lr][lc]      = *(const float4*)(Bsrc + lr * DIM + k0 + lc);
        *(float4*)&Bs[lr + 32][lc] = *(const float4*)(Bsrc + (lr + 32) * DIM + k0 + lc);
        __syncthreads();
        #pragma unroll
        for (int k = 0; k < 32; k += 4) {
            float4 x0 = *(const float4*)&As[ti * 2 + 0][k];
            float4 x1 = *(const float4*)&As[ti * 2 + 1][k];
            float4 wv = *(const float4*)&w3s[k0 + k];
            #pragma unroll
            for (int jj = 0; jj < 4; jj++) {
                float4 b = *(const float4*)&Bs[tj + jj * 16][k];
                acc[0][jj] = fmaf(fabsf(x0.x - b.x), wv.x, acc[0][jj]);
                acc[0][jj] = fmaf(fabsf(x0.y - b.y), wv.y, acc[0][jj]);
                acc[0][jj] = fmaf(fabsf(x0.z - b.z), wv.z, acc[0][jj]);
                acc[0][jj] = fmaf(fabsf(x0.w - b.w), wv.w, acc[0][jj]);
                acc[1][jj] = fmaf(fabsf(x1.x - b.x), wv.x, acc[1][jj]);
                acc[1][jj] = fmaf(fabsf(x1.y - b.y), wv.y, acc[1][jj]);
                acc[1][jj] = fmaf(fabsf(x1.z - b.z), wv.z, acc[1][jj]);
                acc[1][jj] = fmaf(fabsf(x1.w - b.w), wv.w, acc[1][jj]);
            }
        }
        __syncthreads();
    }

    // epilogue: logits = t1[n] + t2[m] + t3 + b ; bce; reduce
    float t1v0 = ws[1024 + i0 + ti * 2];
    float t1v1 = ws[1024 + i0 + ti * 2 + 1];
    float bias = lb[0];
    bool m_is_pos = (j0 < NPOS);   // labels[m] = 1 for m < 512
    float part = 0.f;
    #pragma unroll
    for (int jj = 0; jj < 4; jj++) {
        int j = tj + jj * 16;
        float t2v = ws[1536 + j0 + j];
        float l0 = t1v0 + t2v + acc[0][jj] + bias;
        float l1 = t1v1 + t2v + acc[1][jj] + bias;
        part += softplus_f(m_is_pos ? -l0 : l0);
        part += softplus_f(m_is_pos ? -l1 : l1);
    }
    #pragma unroll
    for (int off = 32; off; off >>= 1) part += __shfl_xor(part, off);
    int lane = tid & 63, wave = tid >> 6;
    if (lane == 0) wsum[wave] = part;
    __syncthreads();
    if (tid == 0)
        atomicAdd(out, (wsum[0] + wsum[1] + wsum[2] + wsum[3]) * (1.f / 1024.f));
}

extern "C" void kernel_launch(void* const* d_in, const int* in_sizes, int n_in,
                              void* d_out, int out_size, void* d_ws, size_t ws_size,
                              hipStream_t stream) {
    (void)in_sizes; (void)n_in; (void)out_size; (void)ws_size;
    const float* pos = (const float*)d_in[0];
    const float* neg = (const float*)d_in[1];
    const float* w   = (const float*)d_in[2];
    const float* lb  = (const float*)d_in[3];
    float* out = (float*)d_out;
    float* ws  = (float*)d_ws;

    prep_kernel<<<256, 256, 0, stream>>>(pos, neg, w, ws, out);
    cosmat_kernel<<<dim3(16, 16), 256, 0, stream>>>(pos, neg, ws);
    closs_kernel<<<128, 256, 0, stream>>>(ws, out);
    bce_kernel<<<dim3(16, 16), 256, 0, stream>>>(pos, neg, w, lb, ws, out);
}

// Round 2
// 107.128 us; speedup vs baseline: 1.1945x; 1.1945x over previous
//
#include <hip/hip_runtime.h>
#include <math.h>

#define NPOS 512
#define NNEG 512
#define DIM  512
#define NB   1024
#define EPSV 1e-5f
#define COS_EPS 1e-8f

// ws layout (floats):
// [0,1024)     inv_norm allv order [pos;neg]
// [1024,1536)  t1  (pos . w1)
// [1536,2560)  t2  (allv . w2)
// [2560, 2560+512*1024) S cos matrix, cols [0,512)=pos.neg^T, [512,1024)=pos.pos^T
#define WS_S_OFF 2560

__device__ __forceinline__ float softplus_f(float x) {
    return fmaxf(x, 0.f) + __logf(1.f + __expf(-fabsf(x)));
}

// ---------------- Kernel 1: norms + t1 + t2 + zero out ----------------
__global__ __launch_bounds__(256) void prep_kernel(
    const float* __restrict__ pos, const float* __restrict__ neg,
    const float* __restrict__ w, float* __restrict__ ws, float* __restrict__ out)
{
    int gtid = blockIdx.x * 256 + threadIdx.x;
    if (gtid == 0) out[0] = 0.f;
    int row  = gtid >> 6;     // one wave per row, 1024 rows (allv order)
    int lane = threadIdx.x & 63;
    if (row >= NB) return;
    bool is_pos = row < NPOS;
    const float* r = is_pos ? pos + row * DIM : neg + (row - NPOS) * DIM;

    const float4* r4  = (const float4*)r + lane * 2;
    const float4* w14 = (const float4*)(w) + lane * 2;
    const float4* w24 = (const float4*)(w + DIM) + lane * 2;
    float4 a0 = r4[0],  a1 = r4[1];
    float4 u0 = w14[0], u1 = w14[1];
    float4 v0 = w24[0], v1 = w24[1];

    float ss  = a0.x*a0.x + a0.y*a0.y + a0.z*a0.z + a0.w*a0.w
              + a1.x*a1.x + a1.y*a1.y + a1.z*a1.z + a1.w*a1.w;
    float dw1 = a0.x*u0.x + a0.y*u0.y + a0.z*u0.z + a0.w*u0.w
              + a1.x*u1.x + a1.y*u1.y + a1.z*u1.z + a1.w*u1.w;
    float dw2 = a0.x*v0.x + a0.y*v0.y + a0.z*v0.z + a0.w*v0.w
              + a1.x*v1.x + a1.y*v1.y + a1.z*v1.z + a1.w*v1.w;

    #pragma unroll
    for (int off = 32; off; off >>= 1) {
        ss  += __shfl_xor(ss, off);
        dw1 += __shfl_xor(dw1, off);
        dw2 += __shfl_xor(dw2, off);
    }
    if (lane == 0) {
        float inv = 1.f / fmaxf(sqrtf(ss), COS_EPS);
        ws[row] = inv;                 // inv norm, allv order
        ws[1536 + row] = dw2;          // t2
        if (is_pos) ws[1024 + row] = dw1;  // t1
    }
}

// ---------------- Kernel 2: fused cos-matrix + abs-diff BCE ----------------
// Tile 32 n x 32 m (allv order), 256 threads, 2x2 accs/thread.
// grid (32, 16): x = m-tile, y = n-tile. 512 blocks -> 8 waves/CU.
__global__ __launch_bounds__(256) void fused_kernel(
    const float* __restrict__ pos, const float* __restrict__ neg,
    const float* __restrict__ w, const float* __restrict__ lb,
    float* __restrict__ ws, float* __restrict__ out)
{
    __shared__ float As[32][36];
    __shared__ float Bs[32][36];
    __shared__ float w3s[512];
    __shared__ float wsum[4];
    float* S = ws + WS_S_OFF;

    int tid = threadIdx.x;
    int i0 = blockIdx.y * 32;       // n (pos rows)
    int j0 = blockIdx.x * 32;       // m (allv rows, [pos;neg])
    const float* Asrc = pos + i0 * DIM;
    const float* Bsrc = (j0 < NPOS) ? (pos + j0 * DIM) : (neg + (j0 - NPOS) * DIM);

    if (tid < 128) *(float4*)&w3s[tid * 4] = *(const float4*)(w + 2 * DIM + tid * 4);

    int lr = tid >> 3;          // 0..31
    int lc = (tid & 7) * 4;     // 0..28
    int ti = tid >> 4;          // 0..15 -> rows 2ti, 2ti+1
    int tj = tid & 15;          // 0..15 -> cols tj, tj+16

    float c00 = 0.f, c01 = 0.f, c10 = 0.f, c11 = 0.f;   // cos dot
    float t00 = 0.f, t01 = 0.f, t10 = 0.f, t11 = 0.f;   // t3

    for (int k0 = 0; k0 < DIM; k0 += 32) {
        *(float4*)&As[lr][lc] = *(const float4*)(Asrc + lr * DIM + k0 + lc);
        *(float4*)&Bs[lr][lc] = *(const float4*)(Bsrc + lr * DIM + k0 + lc);
        __syncthreads();
        #pragma unroll
        for (int k = 0; k < 32; k += 4) {
            float4 a0 = *(const float4*)&As[2 * ti][k];
            float4 a1 = *(const float4*)&As[2 * ti + 1][k];
            float4 b0 = *(const float4*)&Bs[tj][k];
            float4 b1 = *(const float4*)&Bs[tj + 16][k];
            float4 wv = *(const float4*)&w3s[k0 + k];
#define STEP(cmp, wc) \
            c00 = fmaf(a0.cmp, b0.cmp, c00); \
            c01 = fmaf(a0.cmp, b1.cmp, c01); \
            c10 = fmaf(a1.cmp, b0.cmp, c10); \
            c11 = fmaf(a1.cmp, b1.cmp, c11); \
            t00 = fmaf(fabsf(a0.cmp - b0.cmp), wc, t00); \
            t01 = fmaf(fabsf(a0.cmp - b1.cmp), wc, t01); \
            t10 = fmaf(fabsf(a1.cmp - b0.cmp), wc, t10); \
            t11 = fmaf(fabsf(a1.cmp - b1.cmp), wc, t11);
            STEP(x, wv.x) STEP(y, wv.y) STEP(z, wv.z) STEP(w, wv.w)
#undef STEP
        }
        __syncthreads();
    }

    int n0 = i0 + 2 * ti, n1 = n0 + 1;
    int m0 = j0 + tj,     m1 = m0 + 16;

    // --- cos epilogue: normalize, write S (remapped: m<512 is pos -> col 512+m) ---
    float invn0 = ws[n0], invn1 = ws[n1];
    float invm0 = ws[m0], invm1 = ws[m1];
    int cm0 = (j0 < NPOS) ? m0 + NPOS : m0 - NPOS;
    int cm1 = cm0 + 16;
    S[(size_t)n0 * NB + cm0] = c00 * invn0 * invm0;
    S[(size_t)n0 * NB + cm1] = c01 * invn0 * invm1;
    S[(size_t)n1 * NB + cm0] = c10 * invn1 * invm0;
    S[(size_t)n1 * NB + cm1] = c11 * invn1 * invm1;

    // --- bce epilogue ---
    float t1v0 = ws[1024 + n0], t1v1 = ws[1024 + n1];
    float t2v0 = ws[1536 + m0], t2v1 = ws[1536 + m1];
    float bias = lb[0];
    float l00 = t1v0 + t2v0 + t00 + bias;
    float l01 = t1v0 + t2v1 + t01 + bias;
    float l10 = t1v1 + t2v0 + t10 + bias;
    float l11 = t1v1 + t2v1 + t11 + bias;
    bool m_is_pos = (j0 < NPOS);   // label 1 for allv rows < 512
    float part;
    if (m_is_pos)
        part = softplus_f(-l00) + softplus_f(-l01) + softplus_f(-l10) + softplus_f(-l11);
    else
        part = softplus_f(l00) + softplus_f(l01) + softplus_f(l10) + softplus_f(l11);

    #pragma unroll
    for (int off = 32; off; off >>= 1) part += __shfl_xor(part, off);
    int lane = tid & 63, wave = tid >> 6;
    if (lane == 0) wsum[wave] = part;
    __syncthreads();
    if (tid == 0)
        atomicAdd(out, (wsum[0] + wsum[1] + wsum[2] + wsum[3]) * (1.f / 1024.f));
}

// ---------------- Kernel 3: cos-part loss, wave per row ----------------
__global__ __launch_bounds__(256) void closs_kernel(
    const float* __restrict__ ws, float* __restrict__ out)
{
    const float* S = ws + WS_S_OFF;
    int wid  = (blockIdx.x * 256 + threadIdx.x) >> 6;
    int lane = threadIdx.x & 63;
    if (wid >= NPOS) return;
    const float* row = S + (size_t)wid * NB;

    const float4* p = (const float4*)row + lane * 2;
    float4 c0 = p[0], c1 = p[1];
    float deno = __expf(c0.x) + __expf(c0.y) + __expf(c0.z) + __expf(c0.w)
               + __expf(c1.x) + __expf(c1.y) + __expf(c1.z) + __expf(c1.w);
    #pragma unroll
    for (int off = 32; off; off >>= 1) deno += __shfl_xor(deno, off);

    const float4* q = (const float4*)(row + NNEG) + lane * 2;
    float4 d0 = q[0], d1 = q[1];
    float s = 0.f;
    s += __logf(deno + __expf(d0.x) + EPSV) - d0.x;
    s += __logf(deno + __expf(d0.y) + EPSV) - d0.y;
    s += __logf(deno + __expf(d0.z) + EPSV) - d0.z;
    s += __logf(deno + __expf(d0.w) + EPSV) - d0.w;
    s += __logf(deno + __expf(d1.x) + EPSV) - d1.x;
    s += __logf(deno + __expf(d1.y) + EPSV) - d1.y;
    s += __logf(deno + __expf(d1.z) + EPSV) - d1.z;
    s += __logf(deno + __expf(d1.w) + EPSV) - d1.w;
    #pragma unroll
    for (int off = 32; off; off >>= 1) s += __shfl_xor(s, off);
    if (lane == 0) atomicAdd(out, s);
}

extern "C" void kernel_launch(void* const* d_in, const int* in_sizes, int n_in,
                              void* d_out, int out_size, void* d_ws, size_t ws_size,
                              hipStream_t stream) {
    (void)in_sizes; (void)n_in; (void)out_size; (void)ws_size;
    const float* pos = (const float*)d_in[0];
    const float* neg = (const float*)d_in[1];
    const float* w   = (const float*)d_in[2];
    const float* lb  = (const float*)d_in[3];
    float* out = (float*)d_out;
    float* ws  = (float*)d_ws;

    prep_kernel<<<256, 256, 0, stream>>>(pos, neg, w, ws, out);
    fused_kernel<<<dim3(32, 16), 256, 0, stream>>>(pos, neg, w, lb, ws, out);
    closs_kernel<<<128, 256, 0, stream>>>(ws, out);
}

// Round 3
// 104.075 us; speedup vs baseline: 1.2295x; 1.0293x over previous
//
#include <hip/hip_runtime.h>
#include <math.h>

#define NPOS 512
#define DIM  512
#define NB   1024
#define EPSV 1e-5f
#define COS_EPS 1e-8f

// ws float offsets
#define OFF_INV 0                      // [1024] inv norms, allv order [pos;neg]
#define OFF_T1  1024                   // [512]  pos . w1
#define OFF_T2  1536                   // [1024] allv . w2
#define OFF_S0  2560                   // [512*1024] cos partial, k-half 0 (cols = allv m)
#define OFF_S1  (OFF_S0 + NPOS * NB)   // cos partial, k-half 1
#define OFF_TA  (OFF_S1 + NPOS * NB)   // t3 partial, k-half 0
#define OFF_TB  (OFF_TA + NPOS * NB)   // t3 partial, k-half 1

__device__ __forceinline__ float softplus_f(float x) {
    return fmaxf(x, 0.f) + __logf(1.f + __expf(-fabsf(x)));
}

// ---------------- Kernel 1: norms + t1 + t2 + zero out ----------------
__global__ __launch_bounds__(256) void prep_kernel(
    const float* __restrict__ pos, const float* __restrict__ neg,
    const float* __restrict__ w, float* __restrict__ ws, float* __restrict__ out)
{
    int gtid = blockIdx.x * 256 + threadIdx.x;
    if (gtid == 0) out[0] = 0.f;
    int row  = gtid >> 6;     // one wave per row, 1024 rows (allv order)
    int lane = threadIdx.x & 63;
    if (row >= NB) return;
    bool is_pos = row < NPOS;
    const float* r = is_pos ? pos + row * DIM : neg + (row - NPOS) * DIM;

    const float4* r4  = (const float4*)r + lane * 2;
    const float4* w14 = (const float4*)(w) + lane * 2;
    const float4* w24 = (const float4*)(w + DIM) + lane * 2;
    float4 a0 = r4[0],  a1 = r4[1];
    float4 u0 = w14[0], u1 = w14[1];
    float4 v0 = w24[0], v1 = w24[1];

    float ss  = a0.x*a0.x + a0.y*a0.y + a0.z*a0.z + a0.w*a0.w
              + a1.x*a1.x + a1.y*a1.y + a1.z*a1.z + a1.w*a1.w;
    float dw1 = a0.x*u0.x + a0.y*u0.y + a0.z*u0.z + a0.w*u0.w
              + a1.x*u1.x + a1.y*u1.y + a1.z*u1.z + a1.w*u1.w;
    float dw2 = a0.x*v0.x + a0.y*v0.y + a0.z*v0.z + a0.w*v0.w
              + a1.x*v1.x + a1.y*v1.y + a1.z*v1.z + a1.w*v1.w;

    #pragma unroll
    for (int off = 32; off; off >>= 1) {
        ss  += __shfl_xor(ss, off);
        dw1 += __shfl_xor(dw1, off);
        dw2 += __shfl_xor(dw2, off);
    }
    if (lane == 0) {
        float inv = 1.f / fmaxf(sqrtf(ss), COS_EPS);
        ws[OFF_INV + row] = inv;
        ws[OFF_T2 + row]  = dw2;
        if (is_pos) ws[OFF_T1 + row] = dw1;
    }
}

// ---------------- Kernel 2: fused cos + t3 partials ----------------
// 64n x 64m tile, 4x4 per thread (interleaved rows ti+16r, cols tj+16s),
// k-split(2) over grid z. grid (16,8,2) = 256 blocks -> 1 block/CU.
__global__ __launch_bounds__(256) void fused_kernel(
    const float* __restrict__ pos, const float* __restrict__ neg,
    const float* __restrict__ w, float* __restrict__ ws)
{
    __shared__ __align__(16) float As[64][36];
    __shared__ __align__(16) float Bs[64][36];

    const int tid = threadIdx.x;
    const int n0 = blockIdx.y * 64;
    const int m0 = blockIdx.x * 64;
    const int z  = blockIdx.z;
    const float* Asrc = pos + (size_t)n0 * DIM + z * 256;
    const float* Bsrc = ((m0 < NPOS) ? (pos + (size_t)m0 * DIM)
                                     : (neg + (size_t)(m0 - NPOS) * DIM)) + z * 256;
    const float* w3 = w + 2 * DIM + z * 256;

    const int lr = tid >> 3;       // 0..31 staging row
    const int lc = (tid & 7) << 2; // 0..28 staging col
    const int ti = tid >> 4;       // 0..15
    const int tj = tid & 15;       // 0..15

    float c[4][4] = {{0.f}}, t[4][4] = {{0.f}};

    // prologue staging
    float4 a0 = *(const float4*)(Asrc + lr * DIM + lc);
    float4 a1 = *(const float4*)(Asrc + (lr + 32) * DIM + lc);
    float4 b0 = *(const float4*)(Bsrc + lr * DIM + lc);
    float4 b1 = *(const float4*)(Bsrc + (lr + 32) * DIM + lc);
    *(float4*)&As[lr][lc]      = a0;
    *(float4*)&As[lr + 32][lc] = a1;
    *(float4*)&Bs[lr][lc]      = b0;
    *(float4*)&Bs[lr + 32][lc] = b1;
    __syncthreads();

    #pragma unroll 1
    for (int iter = 0; iter < 8; ++iter) {
        const bool more = (iter < 7);
        if (more) {   // prefetch next tile into regs (hides global latency)
            const float* ap = Asrc + (iter + 1) * 32;
            const float* bp = Bsrc + (iter + 1) * 32;
            a0 = *(const float4*)(ap + lr * DIM + lc);
            a1 = *(const float4*)(ap + (lr + 32) * DIM + lc);
            b0 = *(const float4*)(bp + lr * DIM + lc);
            b1 = *(const float4*)(bp + (lr + 32) * DIM + lc);
        }
        const float* w3i = w3 + iter * 32;
        #pragma unroll
        for (int k = 0; k < 32; k += 4) {
            float4 av[4], bv[4];
            #pragma unroll
            for (int r = 0; r < 4; ++r) av[r] = *(const float4*)&As[ti + 16 * r][k];
            #pragma unroll
            for (int s = 0; s < 4; ++s) bv[s] = *(const float4*)&Bs[tj + 16 * s][k];
            const float4 wv = *(const float4*)(w3i + k);  // uniform -> s_load
            #pragma unroll
            for (int r = 0; r < 4; ++r) {
                #pragma unroll
                for (int s = 0; s < 4; ++s) {
                    c[r][s] = fmaf(av[r].x, bv[s].x, c[r][s]);
                    c[r][s] = fmaf(av[r].y, bv[s].y, c[r][s]);
                    c[r][s] = fmaf(av[r].z, bv[s].z, c[r][s]);
                    c[r][s] = fmaf(av[r].w, bv[s].w, c[r][s]);
                    t[r][s] = fmaf(fabsf(av[r].x - bv[s].x), wv.x, t[r][s]);
                    t[r][s] = fmaf(fabsf(av[r].y - bv[s].y), wv.y, t[r][s]);
                    t[r][s] = fmaf(fabsf(av[r].z - bv[s].z), wv.z, t[r][s]);
                    t[r][s] = fmaf(fabsf(av[r].w - bv[s].w), wv.w, t[r][s]);
                }
            }
        }
        if (more) {
            __syncthreads();
            *(float4*)&As[lr][lc]      = a0;
            *(float4*)&As[lr + 32][lc] = a1;
            *(float4*)&Bs[lr][lc]      = b0;
            *(float4*)&Bs[lr + 32][lc] = b1;
            __syncthreads();
        }
    }

    float* Sp = ws + (z ? OFF_S1 : OFF_S0);
    float* Tp = ws + (z ? OFF_TB : OFF_TA);
    #pragma unroll
    for (int r = 0; r < 4; ++r) {
        int n = n0 + ti + 16 * r;
        #pragma unroll
        for (int s = 0; s < 4; ++s) {
            int m = m0 + tj + 16 * s;
            Sp[(size_t)n * NB + m] = c[r][s];
            Tp[(size_t)n * NB + m] = t[r][s];
        }
    }
}

// ---------------- Kernel 3: combine partials + closs + BCE ----------------
// one wave per pos row n; 128 blocks x 256 threads.
__global__ __launch_bounds__(256) void finish_kernel(
    const float* __restrict__ lb, float* __restrict__ ws, float* __restrict__ out)
{
    const int n = blockIdx.x * 4 + (threadIdx.x >> 6);
    const int l = threadIdx.x & 63;
    const float4* S0 = (const float4*)(ws + OFF_S0 + (size_t)n * NB);
    const float4* S1 = (const float4*)(ws + OFF_S1 + (size_t)n * NB);
    const float4* T0 = (const float4*)(ws + OFF_TA + (size_t)n * NB);
    const float4* T1 = (const float4*)(ws + OFF_TB + (size_t)n * NB);
    const float invn = ws[OFF_INV + n];
    const float t1n  = ws[OFF_T1 + n];
    const float bias = lb[0];

    // cols: m = 4*(l + 64j); j=0,1 -> pos (logit_p), j=2,3 -> neg (deno)
    float4 cj[4];
    float eneg = 0.f;
    #pragma unroll
    for (int j = 0; j < 4; ++j) {
        int i4 = l + 64 * j;
        float4 s0 = S0[i4], s1 = S1[i4];
        float4 inv4 = *(const float4*)(ws + OFF_INV + 4 * i4);
        float4 cc;
        cc.x = (s0.x + s1.x) * invn * inv4.x;
        cc.y = (s0.y + s1.y) * invn * inv4.y;
        cc.z = (s0.z + s1.z) * invn * inv4.z;
        cc.w = (s0.w + s1.w) * invn * inv4.w;
        cj[j] = cc;
        if (j >= 2)
            eneg += __expf(cc.x) + __expf(cc.y) + __expf(cc.z) + __expf(cc.w);
    }
    #pragma unroll
    for (int off = 32; off; off >>= 1) eneg += __shfl_xor(eneg, off);

    float part = 0.f;
    #pragma unroll
    for (int j = 0; j < 2; ++j) {
        float4 cc = cj[j];
        part += __logf(eneg + __expf(cc.x) + EPSV) - cc.x;
        part += __logf(eneg + __expf(cc.y) + EPSV) - cc.y;
        part += __logf(eneg + __expf(cc.z) + EPSV) - cc.z;
        part += __logf(eneg + __expf(cc.w) + EPSV) - cc.w;
    }

    float bce = 0.f;
    #pragma unroll
    for (int j = 0; j < 4; ++j) {
        int i4 = l + 64 * j;
        float4 t0 = T0[i4], t1 = T1[i4];
        float4 t2 = *(const float4*)(ws + OFF_T2 + 4 * i4);
        float4 lg;
        lg.x = t1n + t2.x + t0.x + t1.x + bias;
        lg.y = t1n + t2.y + t0.y + t1.y + bias;
        lg.z = t1n + t2.z + t0.z + t1.z + bias;
        lg.w = t1n + t2.w + t0.w + t1.w + bias;
        if (j < 2)
            bce += softplus_f(-lg.x) + softplus_f(-lg.y) + softplus_f(-lg.z) + softplus_f(-lg.w);
        else
            bce += softplus_f(lg.x) + softplus_f(lg.y) + softplus_f(lg.z) + softplus_f(lg.w);
    }
    part += bce * (1.f / 1024.f);

    #pragma unroll
    for (int off = 32; off; off >>= 1) part += __shfl_xor(part, off);
    if (l == 0) atomicAdd(out, part);
}

extern "C" void kernel_launch(void* const* d_in, const int* in_sizes, int n_in,
                              void* d_out, int out_size, void* d_ws, size_t ws_size,
                              hipStream_t stream) {
    (void)in_sizes; (void)n_in; (void)out_size; (void)ws_size;
    const float* pos = (const float*)d_in[0];
    const float* neg = (const float*)d_in[1];
    const float* w   = (const float*)d_in[2];
    const float* lb  = (const float*)d_in[3];
    float* out = (float*)d_out;
    float* ws  = (float*)d_ws;

    prep_kernel<<<256, 256, 0, stream>>>(pos, neg, w, ws, out);
    fused_kernel<<<dim3(16, 8, 2), 256, 0, stream>>>(pos, neg, w, ws);
    finish_kernel<<<128, 256, 0, stream>>>(lb, ws, out);
}